// Round 6
// baseline (357.287 us; speedup 1.0000x reference)
//
#include <hip/hip_runtime.h>
#include <hip/hip_fp16.h>

#define DIM 512
#define N_ITERS 10

typedef float floatx2 __attribute__((ext_vector_type(2)));
typedef float fx4 __attribute__((ext_vector_type(4)));
typedef unsigned int ux2 __attribute__((ext_vector_type(2)));
typedef unsigned int ux4 __attribute__((ext_vector_type(4)));

__device__ __forceinline__ unsigned int pack2h(float lo, float hi) {
    __half2 h = __float22half2_rn(make_float2(lo, hi));
    return *reinterpret_cast<unsigned int*>(&h);
}
__device__ __forceinline__ float2 unpack2h(unsigned int u) {
    return __half22float2(*reinterpret_cast<__half2*>(&u));
}
// pack 4 floats -> 4 fp8 e4m3 in one uint
__device__ __forceinline__ unsigned int pack4f8(float f0, float f1, float f2, float f3) {
    int v = 0;
    v = __builtin_amdgcn_cvt_pk_fp8_f32(f0, f1, v, false);
    v = __builtin_amdgcn_cvt_pk_fp8_f32(f2, f3, v, true);
    return (unsigned int)v;
}

// Merged consts + rowptr + rownorm.
// Writes:
//   consts[0]=a, consts[1]=b, consts[2]=1/(4*s*s)           (thread 0)
//   rstart[r] for r in [0,n]                                 (threads 0..n)
//   xc8: interleaved fp8, row stride 256 uints; per lane uint4
//        {fp8(xn)[0:4], fp8(xn)[4:8], fp8(x)[0:4], fp8(x)[4:8]}
//   xbh: fp16(x*b), row stride DIM
__global__ void __launch_bounds__(256)
prep_kernel(const float* __restrict__ x,
            const float* __restrict__ alpha,
            const float* __restrict__ beta,
            const float* __restrict__ sigma,
            const int* __restrict__ erow, int nnz,
            float* __restrict__ consts,
            int* __restrict__ rstart,
            unsigned int* __restrict__ xc8,
            unsigned short* __restrict__ xbh, int n) {
    int tid = blockIdx.x * blockDim.x + threadIdx.x;
    float b = expf(beta[0]);
    if (tid == 0) {
        float a = expf(alpha[0]);
        float s = expf(sigma[0]);
        consts[0] = a;
        consts[1] = b;
        consts[2] = 1.0f / (4.0f * s * s);
    }
    if (tid <= n) {
        int lo = 0, hi = nnz;
        while (lo < hi) {
            int mid = (lo + hi) >> 1;
            if (erow[mid] < tid) lo = mid + 1; else hi = mid;
        }
        rstart[tid] = lo;
    }
    int wid = tid >> 6;
    int lane = tid & 63;
    if (wid >= n) return;
    const size_t base = (size_t)wid * DIM + lane * 8;
    const fx4* p = (const fx4*)(x + base);
    fx4 u = p[0];
    fx4 v = p[1];
    float s = u.x*u.x + u.y*u.y + u.z*u.z + u.w*u.w
            + v.x*v.x + v.y*v.y + v.z*v.z + v.w*v.w;
    ux4 hb;
    hb.x = pack2h(u.x * b, u.y * b); hb.y = pack2h(u.z * b, u.w * b);
    hb.z = pack2h(v.x * b, v.y * b); hb.w = pack2h(v.z * b, v.w * b);
    *(ux4*)(xbh + base) = hb;
    #pragma unroll
    for (int m = 32; m >= 1; m >>= 1) s += __shfl_xor(s, m, 64);
    float inr = rsqrtf(fmaxf(s, 1e-12f));
    ux4 q;
    q.x = pack4f8(u.x * inr, u.y * inr, u.z * inr, u.w * inr);
    q.y = pack4f8(v.x * inr, v.y * inr, v.z * inr, v.w * inr);
    q.z = pack4f8(u.x, u.y, u.z, u.w);
    q.w = pack4f8(v.x, v.y, v.z, v.w);
    *(ux4*)(xc8 + ((size_t)wid * 256 + lane * 4)) = q;
}

__device__ __forceinline__ float dot8f8(const float* A, unsigned int lo, unsigned int hi) {
    floatx2 p0 = __builtin_amdgcn_cvt_pk_f32_fp8((int)lo, false);
    floatx2 p1 = __builtin_amdgcn_cvt_pk_f32_fp8((int)lo, true);
    floatx2 p2 = __builtin_amdgcn_cvt_pk_f32_fp8((int)hi, false);
    floatx2 p3 = __builtin_amdgcn_cvt_pk_f32_fp8((int)hi, true);
    return A[0]*p0.x + A[1]*p0.y + A[2]*p1.x + A[3]*p1.y
         + A[4]*p2.x + A[5]*p2.y + A[6]*p3.x + A[7]*p3.y;
}

// packed accumulate over 8 dims: acc0..3 are floatx2 -> v_pk_fma_f32
#define ACCP(lo, hi, w2)                                                          \
    do {                                                                          \
        acc0 += (w2) * __builtin_amdgcn_cvt_pk_f32_fp8((int)(lo), false);         \
        acc1 += (w2) * __builtin_amdgcn_cvt_pk_f32_fp8((int)(lo), true);          \
        acc2 += (w2) * __builtin_amdgcn_cvt_pk_f32_fp8((int)(hi), false);         \
        acc3 += (w2) * __builtin_amdgcn_cvt_pk_f32_fp8((int)(hi), true);          \
    } while (0)

// packed accumulate over 4 dims (split-pass iter): acc0..1 floatx2
#define ACCP4(u, w2)                                                              \
    do {                                                                          \
        acc0 += (w2) * __builtin_amdgcn_cvt_pk_f32_fp8((int)(u), false);          \
        acc1 += (w2) * __builtin_amdgcn_cvt_pk_f32_fp8((int)(u), true);           \
    } while (0)

// Fused edge_row + iteration 1. One wave per row (full 512 dims).
__global__ void __launch_bounds__(256)
fused1_kernel(const unsigned int* __restrict__ xc8,
              const float* __restrict__ x,
              const float* __restrict__ eval_,
              const int* __restrict__ ecol,
              const int* __restrict__ rstart,
              const float* __restrict__ consts,
              float* __restrict__ sup, float* __restrict__ inv_denom,
              unsigned short* __restrict__ next16,
              unsigned int* __restrict__ next8, int n) {
    int row = (blockIdx.x * blockDim.x + threadIdx.x) >> 6;
    int lane = threadIdx.x & 63;
    if (row >= n) return;
    const size_t base = (size_t)row * DIM + lane * 8;
    ux4 hr = *(const ux4*)(xc8 + (size_t)row * 256 + lane * 4);
    const fx4* px = (const fx4*)(x + base);
    fx4 u = px[0];
    fx4 v = px[1];
    float A[8];
    {
        floatx2 p0 = __builtin_amdgcn_cvt_pk_f32_fp8((int)hr.x, false);
        floatx2 p1 = __builtin_amdgcn_cvt_pk_f32_fp8((int)hr.x, true);
        floatx2 p2 = __builtin_amdgcn_cvt_pk_f32_fp8((int)hr.y, false);
        floatx2 p3 = __builtin_amdgcn_cvt_pk_f32_fp8((int)hr.y, true);
        A[0]=p0.x; A[1]=p0.y; A[2]=p1.x; A[3]=p1.y;
        A[4]=p2.x; A[5]=p2.y; A[6]=p3.x; A[7]=p3.y;
    }
    float a = consts[0], b = consts[1], c2 = consts[2];
    int rs = rstart[row], re = rstart[row + 1];
    float norm_acc = 0.0f;
    floatx2 acc0 = {0.f, 0.f}, acc1 = {0.f, 0.f}, acc2 = {0.f, 0.f}, acc3 = {0.f, 0.f};
    int e = rs;
    for (; e + 3 < re; e += 4) {
        int c[4]; float ev[4]; ux4 h[4]; float s[4];
        #pragma unroll
        for (int j = 0; j < 4; ++j) { c[j] = ecol[e + j]; ev[j] = eval_[e + j]; }
        #pragma unroll
        for (int j = 0; j < 4; ++j)
            h[j] = *(const ux4*)(xc8 + (size_t)c[j] * 256 + lane * 4);
        #pragma unroll
        for (int j = 0; j < 4; ++j) s[j] = dot8f8(A, h[j].x, h[j].y);
        #pragma unroll
        for (int m = 32; m >= 1; m >>= 1) {
            #pragma unroll
            for (int j = 0; j < 4; ++j) s[j] += __shfl_xor(s[j], m, 64);
        }
        #pragma unroll
        for (int j = 0; j < 4; ++j) {
            float sim = (row == c[j]) ? 0.0f : s[j];
            float sp = ev[j] * expf(sim * c2);
            norm_acc += sp;
            if (lane == 0) sup[e + j] = sp;
            floatx2 w2 = {sp, sp};
            ACCP(h[j].z, h[j].w, w2);
        }
    }
    for (; e < re; ++e) {
        int c0 = ecol[e];
        float ev0 = eval_[e];
        ux4 h0 = *(const ux4*)(xc8 + (size_t)c0 * 256 + lane * 4);
        float s0 = dot8f8(A, h0.x, h0.y);
        #pragma unroll
        for (int m = 32; m >= 1; m >>= 1) s0 += __shfl_xor(s0, m, 64);
        float sim0 = (row == c0) ? 0.0f : s0;
        float sp0 = ev0 * expf(sim0 * c2);
        norm_acc += sp0;
        if (lane == 0) sup[e] = sp0;
        floatx2 w2 = {sp0, sp0};
        ACCP(h0.z, h0.w, w2);
    }
    float inv_d = 1.0f / (b + norm_acc * a + a);
    if (lane == 0) inv_denom[row] = inv_d;
    float r0 = (u.x * b + (acc0.x + u.x) * a) * inv_d;
    float r1 = (u.y * b + (acc0.y + u.y) * a) * inv_d;
    float r2 = (u.z * b + (acc1.x + u.z) * a) * inv_d;
    float r3 = (u.w * b + (acc1.y + u.w) * a) * inv_d;
    float r4 = (v.x * b + (acc2.x + v.x) * a) * inv_d;
    float r5 = (v.y * b + (acc2.y + v.y) * a) * inv_d;
    float r6 = (v.z * b + (acc3.x + v.z) * a) * inv_d;
    float r7 = (v.w * b + (acc3.y + v.w) * a) * inv_d;
    ux4 ho;
    ho.x = pack2h(r0, r1); ho.y = pack2h(r2, r3);
    ho.z = pack2h(r4, r5); ho.w = pack2h(r6, r7);
    *(ux4*)(next16 + base) = ho;
    uint2 q;
    q.x = pack4f8(r0, r1, r2, r3);
    q.y = pack4f8(r4, r5, r6, r7);
    *(uint2*)(next8 + (size_t)row * (DIM / 4) + lane * 2) = q;
}

// XCD-partitioned split iteration: one launch, 2*n/4 blocks.
// blockIdx&7 selects the XCD (empirical round-robin dispatch); XCDs 0-3
// process dims [0,256), XCDs 4-7 dims [256,512). Each XCD's gather
// footprint in prev8 is a contiguous 4 MB half == one XCD L2, so the
// ~10x edge reuse hits L2 instead of refetching from L3/HBM.
// Pure streams (prev16, xbh) are NT loads so they don't evict the
// gather half; stores stay normal (next buffers are next iter's input).
__global__ void __launch_bounds__(256)
iter_kernel(const unsigned short* __restrict__ prev16,
            const unsigned int* __restrict__ prev8,
            unsigned short* __restrict__ next16,
            unsigned int* __restrict__ next8,
            float* __restrict__ out_f32, int last,
            const float* __restrict__ consts, const float* __restrict__ inv_denom,
            const float* __restrict__ sup, const int* __restrict__ ecol,
            const int* __restrict__ rstart,
            const unsigned short* __restrict__ xbh, int n) {
    int bid = blockIdx.x;
    int xcd = bid & 7;
    int pass = xcd >> 2;          // dim half: [pass*256, pass*256+256)
    int sub = xcd & 3;
    int row_block = (bid >> 3) * 4 + sub;          // [0, n/4)
    int row = row_block * 4 + (threadIdx.x >> 6);  // 4 waves/block
    int lane = threadIdx.x & 63;
    if (row >= n) return;
    // element index of this lane's 4 dims within fp16/f32 arrays
    const size_t e16 = (size_t)row * DIM + pass * (DIM / 2) + lane * 4;
    // uint index within fp8 arrays (row stride DIM/4 = 128)
    const size_t g8 = (size_t)pass * (DIM / 8) + lane;
    // issue-early epilogue streams (NT: no reuse, keep out of L2)
    ux2 hs = __builtin_nontemporal_load((const ux2*)(prev16 + e16));
    ux2 hx = __builtin_nontemporal_load((const ux2*)(xbh + e16));
    float a = consts[0];
    float inv_d = inv_denom[row];
    int rs = rstart[row], re = rstart[row + 1];
    floatx2 acc0 = {0.f, 0.f}, acc1 = {0.f, 0.f};
    int e = rs;
    for (; e + 7 < re; e += 8) {
        int c[8]; float w[8]; unsigned int h[8];
        #pragma unroll
        for (int j = 0; j < 8; ++j) { c[j] = ecol[e + j]; w[j] = sup[e + j]; }
        #pragma unroll
        for (int j = 0; j < 8; ++j)
            h[j] = prev8[(size_t)c[j] * (DIM / 4) + g8];
        #pragma unroll
        for (int j = 0; j < 8; ++j) {
            floatx2 w2 = {w[j], w[j]};
            ACCP4(h[j], w2);
        }
    }
    for (; e + 1 < re; e += 2) {
        int c0 = ecol[e], c1 = ecol[e + 1];
        float w0 = sup[e], w1 = sup[e + 1];
        unsigned int h0 = prev8[(size_t)c0 * (DIM / 4) + g8];
        unsigned int h1 = prev8[(size_t)c1 * (DIM / 4) + g8];
        floatx2 w20 = {w0, w0}; ACCP4(h0, w20);
        floatx2 w21 = {w1, w1}; ACCP4(h1, w21);
    }
    if (e < re) {
        float w = sup[e];
        int c = ecol[e];
        unsigned int h = prev8[(size_t)c * (DIM / 4) + g8];
        floatx2 w2 = {w, w}; ACCP4(h, w2);
    }
    float2 s0 = unpack2h(hs.x), s1 = unpack2h(hs.y);
    float2 x0 = unpack2h(hx.x), x1 = unpack2h(hx.y);
    float r0 = (x0.x + (acc0.x + s0.x) * a) * inv_d;
    float r1 = (x0.y + (acc0.y + s0.y) * a) * inv_d;
    float r2 = (x1.x + (acc1.x + s1.x) * a) * inv_d;
    float r3 = (x1.y + (acc1.y + s1.y) * a) * inv_d;
    if (last) {
        fx4 o = {r0, r1, r2, r3};
        *(fx4*)(out_f32 + e16) = o;
    } else {
        ux2 ho;
        ho.x = pack2h(r0, r1); ho.y = pack2h(r2, r3);
        *(ux2*)(next16 + e16) = ho;
        next8[(size_t)row * (DIM / 4) + g8] = pack4f8(r0, r1, r2, r3);
    }
}

extern "C" void kernel_launch(void* const* d_in, const int* in_sizes, int n_in,
                              void* d_out, int out_size, void* d_ws, size_t ws_size,
                              hipStream_t stream) {
    const float* x     = (const float*)d_in[0];
    const float* alpha = (const float*)d_in[1];
    const float* beta  = (const float*)d_in[2];
    const float* sigma = (const float*)d_in[3];
    const float* eval_ = (const float*)d_in[4];
    const int* erow = (const int*)d_in[5];
    const int* ecol = (const int*)d_in[6];

    const int n   = in_sizes[0] / DIM;   // 16384
    const int nnz = in_sizes[4];         // 163840

    float* ws        = (float*)d_ws;
    float* consts    = ws;                            // 64 floats
    float* inv_denom = ws + 64;                       // n
    int*   rstart    = (int*)(inv_denom + n);         // n+1 (+pad)
    float* sup       = (float*)(rstart + n + 64);     // nnz
    unsigned short* xbh    = (unsigned short*)(sup + nnz);           // n*DIM fp16 (16 MB)
    unsigned short* bufB16 = xbh + (size_t)n * DIM;                  // n*DIM fp16 (16 MB)
    unsigned int*   xc8    = (unsigned int*)(bufB16 + (size_t)n * DIM); // n*256 uints (16 MB)
    unsigned int*   bufB8  = xc8 + (size_t)n * 256;                  // 8 MB
    unsigned int*   bufA8  = xc8;   // alias: xc8 dead after fused1_kernel
    unsigned short* bufA16 = (unsigned short*)d_out;                 // first 16 MB of d_out
    float* out_f32 = (float*)d_out;

    // merged consts + rowptr + rownorm
    prep_kernel<<<(n * 64) / 256, 256, 0, stream>>>(x, alpha, beta, sigma,
                                                    erow, nnz, consts, rstart,
                                                    xc8, xbh, n);
    // fused cosine-sim + sup + inv_denom + iteration 1 (writes B buffers)
    fused1_kernel<<<(n * 64) / 256, 256, 0, stream>>>(xc8, x, eval_, ecol, rstart,
                                                      consts, sup, inv_denom,
                                                      bufB16, bufB8, n);
    // iterations 2..10, XCD-split: 2 passes x (n/4 rows-blocks) per launch
    const int iter_blocks = 2 * (n / 4);   // 8192
    for (int k = 0; k < N_ITERS - 1; ++k) {
        const unsigned short* prev16 = (k & 1) ? bufA16 : bufB16;
        const unsigned int*   prev8  = (k & 1) ? bufA8  : bufB8;
        unsigned short* next16 = (k & 1) ? bufB16 : bufA16;
        unsigned int*   next8  = (k & 1) ? bufB8  : bufA8;
        int last = (k == N_ITERS - 2) ? 1 : 0;
        iter_kernel<<<iter_blocks, 256, 0, stream>>>(prev16, prev8, next16, next8,
                                                     out_f32, last,
                                                     consts, inv_denom, sup, ecol,
                                                     rstart, xbh, n);
    }
}

// Round 7
// 332.462 us; speedup vs baseline: 1.0747x; 1.0747x over previous
//
#include <hip/hip_runtime.h>
#include <hip/hip_fp16.h>

#define DIM 512
#define N_ITERS 10

typedef float floatx2 __attribute__((ext_vector_type(2)));
typedef float fx4 __attribute__((ext_vector_type(4)));
typedef unsigned int ux2 __attribute__((ext_vector_type(2)));
typedef unsigned int ux4 __attribute__((ext_vector_type(4)));

__device__ __forceinline__ unsigned int pack2h(float lo, float hi) {
    __half2 h = __float22half2_rn(make_float2(lo, hi));
    return *reinterpret_cast<unsigned int*>(&h);
}
__device__ __forceinline__ float2 unpack2h(unsigned int u) {
    return __half22float2(*reinterpret_cast<__half2*>(&u));
}
// pack 4 floats -> 4 fp8 e4m3 in one uint
__device__ __forceinline__ unsigned int pack4f8(float f0, float f1, float f2, float f3) {
    int v = 0;
    v = __builtin_amdgcn_cvt_pk_fp8_f32(f0, f1, v, false);
    v = __builtin_amdgcn_cvt_pk_fp8_f32(f2, f3, v, true);
    return (unsigned int)v;
}

// Merged consts + rowptr + rownorm.
// Writes:
//   consts[0]=a, consts[1]=b, consts[2]=1/(4*s*s)           (thread 0)
//   rstart[r] for r in [0,n]                                 (threads 0..n)
//   xn8:   fp8(x/||x||), row stride DIM/4=128 uints, uint2/lane
//   norms: ||x_row|| f32 (64 KB, L2-resident in fused1)
//   xbh:   fp16(x*b), row stride DIM
__global__ void __launch_bounds__(256)
prep_kernel(const float* __restrict__ x,
            const float* __restrict__ alpha,
            const float* __restrict__ beta,
            const float* __restrict__ sigma,
            const int* __restrict__ erow, int nnz,
            float* __restrict__ consts,
            int* __restrict__ rstart,
            unsigned int* __restrict__ xn8,
            float* __restrict__ norms,
            unsigned short* __restrict__ xbh, int n) {
    int tid = blockIdx.x * blockDim.x + threadIdx.x;
    float b = expf(beta[0]);
    if (tid == 0) {
        float a = expf(alpha[0]);
        float s = expf(sigma[0]);
        consts[0] = a;
        consts[1] = b;
        consts[2] = 1.0f / (4.0f * s * s);
    }
    if (tid <= n) {
        int lo = 0, hi = nnz;
        while (lo < hi) {
            int mid = (lo + hi) >> 1;
            if (erow[mid] < tid) lo = mid + 1; else hi = mid;
        }
        rstart[tid] = lo;
    }
    int wid = tid >> 6;
    int lane = tid & 63;
    if (wid >= n) return;
    const size_t base = (size_t)wid * DIM + lane * 8;
    const fx4* p = (const fx4*)(x + base);
    fx4 u = p[0];
    fx4 v = p[1];
    float s = u.x*u.x + u.y*u.y + u.z*u.z + u.w*u.w
            + v.x*v.x + v.y*v.y + v.z*v.z + v.w*v.w;
    ux4 hb;
    hb.x = pack2h(u.x * b, u.y * b); hb.y = pack2h(u.z * b, u.w * b);
    hb.z = pack2h(v.x * b, v.y * b); hb.w = pack2h(v.z * b, v.w * b);
    *(ux4*)(xbh + base) = hb;
    #pragma unroll
    for (int m = 32; m >= 1; m >>= 1) s += __shfl_xor(s, m, 64);
    float inr = rsqrtf(fmaxf(s, 1e-12f));
    if (lane == 0) norms[wid] = s * inr;   // = sqrt(s); 0 when s==0
    ux2 qn;
    qn.x = pack4f8(u.x * inr, u.y * inr, u.z * inr, u.w * inr);
    qn.y = pack4f8(v.x * inr, v.y * inr, v.z * inr, v.w * inr);
    *(ux2*)(xn8 + ((size_t)wid * (DIM / 4) + lane * 2)) = qn;
}

__device__ __forceinline__ float dot8f8(const float* A, unsigned int lo, unsigned int hi) {
    floatx2 p0 = __builtin_amdgcn_cvt_pk_f32_fp8((int)lo, false);
    floatx2 p1 = __builtin_amdgcn_cvt_pk_f32_fp8((int)lo, true);
    floatx2 p2 = __builtin_amdgcn_cvt_pk_f32_fp8((int)hi, false);
    floatx2 p3 = __builtin_amdgcn_cvt_pk_f32_fp8((int)hi, true);
    return A[0]*p0.x + A[1]*p0.y + A[2]*p1.x + A[3]*p1.y
         + A[4]*p2.x + A[5]*p2.y + A[6]*p3.x + A[7]*p3.y;
}

// packed accumulate over 8 dims: acc0..3 are floatx2 -> v_pk_fma_f32
#define ACCP(lo, hi, w2)                                                          \
    do {                                                                          \
        acc0 += (w2) * __builtin_amdgcn_cvt_pk_f32_fp8((int)(lo), false);         \
        acc1 += (w2) * __builtin_amdgcn_cvt_pk_f32_fp8((int)(lo), true);          \
        acc2 += (w2) * __builtin_amdgcn_cvt_pk_f32_fp8((int)(hi), false);         \
        acc3 += (w2) * __builtin_amdgcn_cvt_pk_f32_fp8((int)(hi), true);          \
    } while (0)

// Fused edge_row + iteration 1. One wave per row.
// Single 8B/lane gather of fp8(xn) per edge serves BOTH the cosine-sim dot
// and the axpy (via x[c] = xn[c]*norms[c]) -- halves fused1's gather bytes
// vs the interleaved-16B layout. Epilogue derives x*b and x*a from xbh
// (fp16, 16 MB) instead of reading f32 x (32 MB).
__global__ void __launch_bounds__(256)
fused1_kernel(const unsigned int* __restrict__ xn8,
              const float* __restrict__ norms,
              const float* __restrict__ eval_,
              const int* __restrict__ ecol,
              const int* __restrict__ rstart,
              const float* __restrict__ consts,
              float* __restrict__ sup, float* __restrict__ inv_denom,
              const unsigned short* __restrict__ xbh,
              unsigned short* __restrict__ next16,
              unsigned int* __restrict__ next8, int n) {
    int row = (blockIdx.x * blockDim.x + threadIdx.x) >> 6;
    int lane = threadIdx.x & 63;
    if (row >= n) return;
    const size_t base = (size_t)row * DIM + lane * 8;
    // issue-early: self xn row + epilogue xb row
    ux2 hr = *(const ux2*)(xn8 + (size_t)row * (DIM / 4) + lane * 2);
    ux4 hx = *(const ux4*)(xbh + base);
    float A[8];
    {
        floatx2 p0 = __builtin_amdgcn_cvt_pk_f32_fp8((int)hr.x, false);
        floatx2 p1 = __builtin_amdgcn_cvt_pk_f32_fp8((int)hr.x, true);
        floatx2 p2 = __builtin_amdgcn_cvt_pk_f32_fp8((int)hr.y, false);
        floatx2 p3 = __builtin_amdgcn_cvt_pk_f32_fp8((int)hr.y, true);
        A[0]=p0.x; A[1]=p0.y; A[2]=p1.x; A[3]=p1.y;
        A[4]=p2.x; A[5]=p2.y; A[6]=p3.x; A[7]=p3.y;
    }
    float a = consts[0], b = consts[1], c2 = consts[2];
    int rs = rstart[row], re = rstart[row + 1];
    float norm_acc = 0.0f;
    floatx2 acc0 = {0.f, 0.f}, acc1 = {0.f, 0.f}, acc2 = {0.f, 0.f}, acc3 = {0.f, 0.f};
    int e = rs;
    for (; e + 3 < re; e += 4) {
        int c[4]; float ev[4]; float nr[4]; ux2 h[4]; float s[4];
        #pragma unroll
        for (int j = 0; j < 4; ++j) { c[j] = ecol[e + j]; ev[j] = eval_[e + j]; }
        #pragma unroll
        for (int j = 0; j < 4; ++j) nr[j] = norms[c[j]];
        #pragma unroll
        for (int j = 0; j < 4; ++j)
            h[j] = *(const ux2*)(xn8 + (size_t)c[j] * (DIM / 4) + lane * 2);
        #pragma unroll
        for (int j = 0; j < 4; ++j) s[j] = dot8f8(A, h[j].x, h[j].y);
        #pragma unroll
        for (int m = 32; m >= 1; m >>= 1) {
            #pragma unroll
            for (int j = 0; j < 4; ++j) s[j] += __shfl_xor(s[j], m, 64);
        }
        #pragma unroll
        for (int j = 0; j < 4; ++j) {
            float sim = (row == c[j]) ? 0.0f : s[j];
            float sp = ev[j] * expf(sim * c2);
            norm_acc += sp;
            if (lane == 0) sup[e + j] = sp;
            float w = sp * nr[j];
            floatx2 w2 = {w, w};
            ACCP(h[j].x, h[j].y, w2);
        }
    }
    for (; e < re; ++e) {
        int c0 = ecol[e];
        float ev0 = eval_[e];
        float nr0 = norms[c0];
        ux2 h0 = *(const ux2*)(xn8 + (size_t)c0 * (DIM / 4) + lane * 2);
        float s0 = dot8f8(A, h0.x, h0.y);
        #pragma unroll
        for (int m = 32; m >= 1; m >>= 1) s0 += __shfl_xor(s0, m, 64);
        float sim0 = (row == c0) ? 0.0f : s0;
        float sp0 = ev0 * expf(sim0 * c2);
        norm_acc += sp0;
        if (lane == 0) sup[e] = sp0;
        float w = sp0 * nr0;
        floatx2 w2 = {w, w};
        ACCP(h0.x, h0.y, w2);
    }
    float inv_d = 1.0f / (b + norm_acc * a + a);
    if (lane == 0) inv_denom[row] = inv_d;
    // out1 = (x*b + (Ax0 + x)*a) * inv_d
    //      = xb*(1 + a/b)*inv_d + Ax0*a*inv_d      (xb from fp16 xbh)
    float kx = (1.0f + a / b) * inv_d;
    float ka = a * inv_d;
    float2 x0 = unpack2h(hx.x), x1 = unpack2h(hx.y);
    float2 x2 = unpack2h(hx.z), x3 = unpack2h(hx.w);
    float r0 = x0.x * kx + acc0.x * ka;
    float r1 = x0.y * kx + acc0.y * ka;
    float r2 = x1.x * kx + acc1.x * ka;
    float r3 = x1.y * kx + acc1.y * ka;
    float r4 = x2.x * kx + acc2.x * ka;
    float r5 = x2.y * kx + acc2.y * ka;
    float r6 = x3.x * kx + acc3.x * ka;
    float r7 = x3.y * kx + acc3.y * ka;
    ux4 ho;
    ho.x = pack2h(r0, r1); ho.y = pack2h(r2, r3);
    ho.z = pack2h(r4, r5); ho.w = pack2h(r6, r7);
    *(ux4*)(next16 + base) = ho;
    uint2 q;
    q.x = pack4f8(r0, r1, r2, r3);
    q.y = pack4f8(r4, r5, r6, r7);
    *(uint2*)(next8 + (size_t)row * (DIM / 4) + lane * 2) = q;
}

// one wave per row; lane owns cols 8L..8L+7; gathers fp8, self/epilogue fp16.
// (identical to the round-5 best: no NT, full-dim, uint2 gathers,
// issue-early self-state loads)
__global__ void __launch_bounds__(256)
iter_kernel(const unsigned short* __restrict__ prev16,
            const unsigned int* __restrict__ prev8,
            unsigned short* __restrict__ next16,
            unsigned int* __restrict__ next8,
            float* __restrict__ out_f32, int last,
            const float* __restrict__ consts, const float* __restrict__ inv_denom,
            const float* __restrict__ sup, const int* __restrict__ ecol,
            const int* __restrict__ rstart,
            const unsigned short* __restrict__ xbh, int n) {
    int row = (blockIdx.x * blockDim.x + threadIdx.x) >> 6;
    int lane = threadIdx.x & 63;
    if (row >= n) return;
    const size_t loff16 = lane * 8;
    const size_t base16 = (size_t)row * DIM + loff16;
    const size_t loff8 = lane * 2;
    // issue-early epilogue streams
    ux4 hs = *(const ux4*)(prev16 + base16);
    ux4 hx = *(const ux4*)(xbh + base16);
    float a = consts[0];
    float inv_d = inv_denom[row];
    int rs = rstart[row], re = rstart[row + 1];
    floatx2 acc0 = {0.f, 0.f}, acc1 = {0.f, 0.f}, acc2 = {0.f, 0.f}, acc3 = {0.f, 0.f};
    int e = rs;
    for (; e + 7 < re; e += 8) {
        int c[8]; float w[8]; uint2 h[8];
        #pragma unroll
        for (int j = 0; j < 8; ++j) { c[j] = ecol[e + j]; w[j] = sup[e + j]; }
        #pragma unroll
        for (int j = 0; j < 8; ++j)
            h[j] = *(const uint2*)(prev8 + (size_t)c[j] * (DIM / 4) + loff8);
        #pragma unroll
        for (int j = 0; j < 8; ++j) {
            floatx2 w2 = {w[j], w[j]};
            ACCP(h[j].x, h[j].y, w2);
        }
    }
    for (; e + 1 < re; e += 2) {
        int c0 = ecol[e], c1 = ecol[e + 1];
        float w0 = sup[e], w1 = sup[e + 1];
        uint2 h0 = *(const uint2*)(prev8 + (size_t)c0 * (DIM / 4) + loff8);
        uint2 h1 = *(const uint2*)(prev8 + (size_t)c1 * (DIM / 4) + loff8);
        floatx2 w20 = {w0, w0}; ACCP(h0.x, h0.y, w20);
        floatx2 w21 = {w1, w1}; ACCP(h1.x, h1.y, w21);
    }
    if (e < re) {
        float w = sup[e];
        int c = ecol[e];
        uint2 h = *(const uint2*)(prev8 + (size_t)c * (DIM / 4) + loff8);
        floatx2 w2 = {w, w}; ACCP(h.x, h.y, w2);
    }
    float2 s0 = unpack2h(hs.x), s1 = unpack2h(hs.y);
    float2 s2 = unpack2h(hs.z), s3 = unpack2h(hs.w);
    float2 x0 = unpack2h(hx.x), x1 = unpack2h(hx.y);
    float2 x2 = unpack2h(hx.z), x3 = unpack2h(hx.w);
    float r0 = (x0.x + (acc0.x + s0.x) * a) * inv_d;
    float r1 = (x0.y + (acc0.y + s0.y) * a) * inv_d;
    float r2 = (x1.x + (acc1.x + s1.x) * a) * inv_d;
    float r3 = (x1.y + (acc1.y + s1.y) * a) * inv_d;
    float r4 = (x2.x + (acc2.x + s2.x) * a) * inv_d;
    float r5 = (x2.y + (acc2.y + s2.y) * a) * inv_d;
    float r6 = (x3.x + (acc3.x + s3.x) * a) * inv_d;
    float r7 = (x3.y + (acc3.y + s3.y) * a) * inv_d;
    if (last) {
        fx4* o = (fx4*)(out_f32 + base16);
        fx4 o0 = {r0, r1, r2, r3};
        fx4 o1 = {r4, r5, r6, r7};
        o[0] = o0;
        o[1] = o1;
    } else {
        ux4 ho;
        ho.x = pack2h(r0, r1); ho.y = pack2h(r2, r3);
        ho.z = pack2h(r4, r5); ho.w = pack2h(r6, r7);
        *(ux4*)(next16 + base16) = ho;
        uint2 q;
        q.x = pack4f8(r0, r1, r2, r3);
        q.y = pack4f8(r4, r5, r6, r7);
        *(uint2*)(next8 + (size_t)row * (DIM / 4) + loff8) = q;
    }
}

extern "C" void kernel_launch(void* const* d_in, const int* in_sizes, int n_in,
                              void* d_out, int out_size, void* d_ws, size_t ws_size,
                              hipStream_t stream) {
    const float* x     = (const float*)d_in[0];
    const float* alpha = (const float*)d_in[1];
    const float* beta  = (const float*)d_in[2];
    const float* sigma = (const float*)d_in[3];
    const float* eval_ = (const float*)d_in[4];
    const int* erow = (const int*)d_in[5];
    const int* ecol = (const int*)d_in[6];

    const int n   = in_sizes[0] / DIM;   // 16384
    const int nnz = in_sizes[4];         // 163840

    float* ws        = (float*)d_ws;
    float* consts    = ws;                            // 64 floats
    float* inv_denom = ws + 64;                       // n
    int*   rstart    = (int*)(inv_denom + n);         // n+1 (+pad)
    float* sup       = (float*)(rstart + n + 64);     // nnz
    float* norms     = sup + nnz;                     // n
    unsigned short* xbh    = (unsigned short*)(norms + n);           // n*DIM fp16 (16 MB)
    unsigned short* bufB16 = xbh + (size_t)n * DIM;                  // n*DIM fp16 (16 MB)
    unsigned int*   xn8    = (unsigned int*)(bufB16 + (size_t)n * DIM); // n*DIM/4 uints (8 MB)
    unsigned int*   bufB8  = xn8 + (size_t)n * (DIM / 4);            // 8 MB
    unsigned int*   bufA8  = xn8;   // alias: xn8 dead after fused1_kernel;
                                    // bufA8 first written by the k=0 iter launch
    unsigned short* bufA16 = (unsigned short*)d_out;                 // first 16 MB of d_out
    float* out_f32 = (float*)d_out;

    // merged consts + rowptr + rownorm
    prep_kernel<<<(n * 64) / 256, 256, 0, stream>>>(x, alpha, beta, sigma,
                                                    erow, nnz, consts, rstart,
                                                    xn8, norms, xbh, n);
    // fused cosine-sim + sup + inv_denom + iteration 1 (writes B buffers)
    fused1_kernel<<<(n * 64) / 256, 256, 0, stream>>>(xn8, norms, eval_, ecol, rstart,
                                                      consts, sup, inv_denom, xbh,
                                                      bufB16, bufB8, n);
    // iterations 2..10: k even reads B writes A; k odd reads A writes B;
    // k=8 (iteration 10) reads B and writes fp32 d_out.
    for (int k = 0; k < N_ITERS - 1; ++k) {
        const unsigned short* prev16 = (k & 1) ? bufA16 : bufB16;
        const unsigned int*   prev8  = (k & 1) ? bufA8  : bufB8;
        unsigned short* next16 = (k & 1) ? bufB16 : bufA16;
        unsigned int*   next8  = (k & 1) ? bufB8  : bufA8;
        int last = (k == N_ITERS - 2) ? 1 : 0;
        iter_kernel<<<(n * 64) / 256, 256, 0, stream>>>(prev16, prev8, next16, next8,
                                                        out_f32, last,
                                                        consts, inv_denom, sup, ecol,
                                                        rstart, xbh, n);
    }
}